// Round 8
// baseline (112.582 us; speedup 1.0000x reference)
//
#include <hip/hip_runtime.h>

// SememeEmbeddingKNN, 2-kernel decomposition.
//   emb      [V=50257, H=1024] f32   (206 MB -> L3-resident)
//   word_ids [L=256, W=16]     i32
//   sem_ids  [L=256, W=16, S=32] i32
//   out      [L, H] f32
//
// R7 -> R8: aggregate gather rate tracks WAVE COUNT (R3: 131072 waves ->
// 12.6 TB/s; R5/R6: 65536 -> 7-8.6 TB/s). Recover 131072 waves at low
// bytes: wave = (b, sememe-QUAD, quarter-row); 5 independent float4 loads
// per wave (4 sememe + 1 word quarter), no LDS/barrier in phase A, no nt.
// The 4 waves of a block cover the 4 quarters of the SAME quad -> block
// footprint = 4 sememe rows + 1 word row read exactly once.
// __launch_bounds__(256,8) pins <=64 VGPR -> 32 waves/CU.
// BC (unchanged from R6): select (strict '>', earliest index on ties = jax
// top_k) fused with float4 gather/accumulate. No atomics, no memset.

#define HDIM 1024
#define SNUM 32
#define WNUM 16
#define KNN  3

// ---------------- Phase A: partial distances (wave per b,quad,quarter) ----
__global__ __launch_bounds__(256, 8) void knn_dist_kernel(
    const float* __restrict__ emb,
    const int*   __restrict__ word_ids,
    const int*   __restrict__ sem_ids,
    float*       __restrict__ dist_part,   // [4][nj]
    int nj)
{
    const int wave = threadIdx.x >> 6;     // quarter 0..3
    const int lane = threadIdx.x & 63;
    const int blk  = blockIdx.x;           // b*8 + quad
    const int b    = blk >> 3;
    const int quad = blk & 7;

    const int base_s  = b * SNUM + quad * 4;
    const int col     = wave * 256 + 4 * lane;

    const int  wid = word_ids[b];
    const int4 sa  = *(const int4*)(sem_ids + base_s);   // block-uniform

    // 5 independent float4 loads (word first).
    const float4 w  = *(const float4*)(emb + (size_t)wid  * HDIM + col);
    const float4 s0 = *(const float4*)(emb + (size_t)sa.x * HDIM + col);
    const float4 s1 = *(const float4*)(emb + (size_t)sa.y * HDIM + col);
    const float4 s2 = *(const float4*)(emb + (size_t)sa.z * HDIM + col);
    const float4 s3 = *(const float4*)(emb + (size_t)sa.w * HDIM + col);

    float d[4];
    {
        const float dx = s0.x - w.x, dy = s0.y - w.y, dz = s0.z - w.z, dw = s0.w - w.w;
        d[0] = (dx * dx + dy * dy) + (dz * dz + dw * dw);
    }
    {
        const float dx = s1.x - w.x, dy = s1.y - w.y, dz = s1.z - w.z, dw = s1.w - w.w;
        d[1] = (dx * dx + dy * dy) + (dz * dz + dw * dw);
    }
    {
        const float dx = s2.x - w.x, dy = s2.y - w.y, dz = s2.z - w.z, dw = s2.w - w.w;
        d[2] = (dx * dx + dy * dy) + (dz * dz + dw * dw);
    }
    {
        const float dx = s3.x - w.x, dy = s3.y - w.y, dz = s3.z - w.z, dw = s3.w - w.w;
        d[3] = (dx * dx + dy * dy) + (dz * dz + dw * dw);
    }

    // 4 independent 6-deep butterfly chains (pipelined).
    #pragma unroll
    for (int k = 0; k < 4; ++k) {
        #pragma unroll
        for (int off = 32; off >= 1; off >>= 1)
            d[k] += __shfl_xor(d[k], off, 64);
    }

    if (lane == 0)
        *(float4*)(dist_part + (size_t)wave * nj + base_s) =
            make_float4(d[0], d[1], d[2], d[3]);
}

// ------------- Phase BC: select (top-3) + gather/accumulate, fused --------
__global__ __launch_bounds__(256) void knn_outsel_kernel(
    const float* __restrict__ emb,
    const float* __restrict__ dist_part,   // [4][nj]
    const int*   __restrict__ word_ids,
    const int*   __restrict__ sem_ids,
    float*       __restrict__ out,
    int nj)
{
    const int l = blockIdx.x;
    const int t = threadIdx.x;

    __shared__ int s_ids[WNUM * 4];

    // Stage 1: threads 0..15 each select for one word.
    if (t < WNUM) {
        const int b = l * WNUM + t;
        float4 acc[8];
        #pragma unroll
        for (int i = 0; i < 8; ++i) acc[i] = make_float4(0.f, 0.f, 0.f, 0.f);
        #pragma unroll
        for (int q = 0; q < 4; ++q) {
            const float4* p = (const float4*)(dist_part + (size_t)q * nj + b * SNUM);
            #pragma unroll
            for (int i = 0; i < 8; ++i) {
                const float4 v = p[i];
                acc[i].x += v.x; acc[i].y += v.y; acc[i].z += v.z; acc[i].w += v.w;
            }
        }
        float dl[SNUM];
        #pragma unroll
        for (int i = 0; i < 8; ++i) {
            dl[4 * i + 0] = acc[i].x;
            dl[4 * i + 1] = acc[i].y;
            dl[4 * i + 2] = acc[i].z;
            dl[4 * i + 3] = acc[i].w;
        }
        // Top-3 descending; strict '>' keeps earliest index (= jax top_k).
        unsigned chosen = 0;
        #pragma unroll
        for (int k = 0; k < KNN; ++k) {
            float best = -1.0f;
            int   bi   = 0;
            #pragma unroll
            for (int s = 0; s < SNUM; ++s) {
                if (!((chosen >> s) & 1u) && dl[s] > best) { best = dl[s]; bi = s; }
            }
            chosen |= (1u << bi);
            s_ids[t * 4 + k] = sem_ids[b * SNUM + bi];
        }
        s_ids[t * 4 + 3] = word_ids[b];
    }
    __syncthreads();

    // Stage 2: all 256 threads gather float4 at h = 4t.
    const float third = 1.0f / 3.0f;
    float ax = 0.f, ay = 0.f, az = 0.f, aw = 0.f;
    #pragma unroll 4
    for (int w = 0; w < WNUM; ++w) {
        const float4 e0 = *(const float4*)(emb + (size_t)s_ids[w * 4 + 0] * HDIM + 4 * t);
        const float4 e1 = *(const float4*)(emb + (size_t)s_ids[w * 4 + 1] * HDIM + 4 * t);
        const float4 e2 = *(const float4*)(emb + (size_t)s_ids[w * 4 + 2] * HDIM + 4 * t);
        const float4 ew = *(const float4*)(emb + (size_t)s_ids[w * 4 + 3] * HDIM + 4 * t);
        ax += (e0.x + e1.x + e2.x) * third + ew.x;
        ay += (e0.y + e1.y + e2.y) * third + ew.y;
        az += (e0.z + e1.z + e2.z) * third + ew.z;
        aw += (e0.w + e1.w + e2.w) * third + ew.w;
    }
    const float scale = 0.5f / 16.0f;
    *(float4*)(out + (size_t)l * HDIM + 4 * t) =
        make_float4(ax * scale, ay * scale, az * scale, aw * scale);
}

extern "C" void kernel_launch(void* const* d_in, const int* in_sizes, int n_in,
                              void* d_out, int out_size, void* d_ws, size_t ws_size,
                              hipStream_t stream) {
    const float* emb  = (const float*)d_in[0];
    const int*   wids = (const int*)d_in[1];
    const int*   sids = (const int*)d_in[2];
    float*       out  = (float*)d_out;

    const int nb = in_sizes[1];          // L*W = 4096
    const int nj = in_sizes[2];          // L*W*S = 131072
    const int L  = out_size / HDIM;      // 256

    float* dist_part = (float*)d_ws;     // 4*nj floats (2 MB)

    knn_dist_kernel<<<dim3(nb * 8), dim3(256), 0, stream>>>(emb, wids, sids, dist_part, nj);
    knn_outsel_kernel<<<dim3(L), dim3(256), 0, stream>>>(emb, dist_part, wids, sids, out, nj);
}